// Round 6
// baseline (115.251 us; speedup 1.0000x reference)
//
#include <hip/hip_runtime.h>
#include <stdint.h>

typedef int   int4v   __attribute__((ext_vector_type(4)));
typedef int   int16v  __attribute__((ext_vector_type(16)));
typedef float float4v __attribute__((ext_vector_type(4)));

static constexpr int DIM = 4096;          // N = IN = OUT
static constexpr int BM  = 256, BN = 256; // block tile
static constexpr int BK  = 128;           // K-step bytes (4 MFMA k-steps of K=32)
static constexpr int NKT = DIM / BK;      // 32

// ---------------- quantization kernels ----------------
__global__ __launch_bounds__(256) void quant_act_kernel(
    const float* __restrict__ x, const float* __restrict__ s_ptr,
    const int* __restrict__ zp_ptr, int* __restrict__ out, int n4) {
  const float s  = s_ptr[0];
  const int   zp = zp_ptr[0];
  int idx    = blockIdx.x * blockDim.x + threadIdx.x;
  int stride = gridDim.x * blockDim.x;
  for (int i = idx; i < n4; i += stride) {
    float4v v = reinterpret_cast<const float4v*>(x)[i];
    int packed = 0;
#pragma unroll
    for (int j = 0; j < 4; ++j) {
      int q = (int)rintf(v[j] / s) + zp;
      q = min(max(q, 0), 255);
      q -= zp;
      packed |= (q & 255) << (8 * j);
    }
    out[i] = packed;
  }
}

__global__ __launch_bounds__(256) void quant_wgt_kernel(
    const float* __restrict__ w, const float* __restrict__ ws,
    const int* __restrict__ wzp, int* __restrict__ out, int n4) {
  int idx    = blockIdx.x * blockDim.x + threadIdx.x;
  int stride = gridDim.x * blockDim.x;
  for (int i = idx; i < n4; i += stride) {
    const int row = i >> 10;
    const float s = ws[row];
    const int  zp = wzp[row];
    float4v v = reinterpret_cast<const float4v*>(w)[i];
    int packed = 0;
#pragma unroll
    for (int j = 0; j < 4; ++j) {
      int q = (int)rintf(v[j] / s) + zp;
      q = min(max(q, 0), 255);
      q -= zp;
      packed |= (q & 255) << (8 * j);
    }
    out[i] = packed;
  }
}

// ---- int8 GEMM: 256^2, 8 waves, mfma_i32_32x32x32_i8, 2 barriers/K-tile,
//      read-ahead one quadrant with explicit counted lgkmcnt + sched_barrier fences.
// Wave tile 128x64 = 4m x 2n of 32x32. Frag groups: af0 = m0-1 (8 reads),
// af1 = m2-3 (8), bf[0] = n0 (4), bf[1] = n1 (4). Steady-state lgkm ledger
// entering ph1: 12 outstanding (af0+bf0 of kt, issued in ph4 of kt-1).

__global__ __launch_bounds__(512) void gemm_i8_32x32(
    const signed char* __restrict__ A, const signed char* __restrict__ B,
    const float* __restrict__ s_act, const float* __restrict__ w_scale,
    const float* __restrict__ bias, float* __restrict__ C) {
  extern __shared__ signed char smem[];  // 2 x (A 32K + B 32K) = 128 KiB

  const int tid  = threadIdx.x;
  const int w    = tid >> 6;            // wave 0..7
  const int lane = tid & 63;
  const int wr = w >> 2, wc = w & 3;    // 2 x 4 wave grid; wave tile 128x64
  const int row31 = lane & 31, khalf = lane >> 5;
  const int swk = (row31 & 7) << 4;     // read-side XOR swizzle key

  const int srow = lane >> 3;                           // staging row within 8-row chunk
  const int scol = ((lane & 7) ^ (lane >> 3)) << 4;     // pre-swizzled global col

  const int tileM = blockIdx.y * BM;
  const int tileN = blockIdx.x * BN;

  auto stageA = [&](int i, int t) {
    signed char* dst = smem + (t & 1) * 65536;
    const int c = 4 * w + i;
    const size_t g = (size_t)(tileM + c * 8 + srow) * DIM + (size_t)t * BK + scol;
    __builtin_amdgcn_global_load_lds(
        (const __attribute__((address_space(1))) void*)(A + g),
        (__attribute__((address_space(3))) void*)(dst + c * 1024), 16, 0, 0);
  };
  auto stageB = [&](int i, int t) {
    signed char* dst = smem + (t & 1) * 65536 + 32768;
    const int c = 4 * w + i;
    const size_t g = (size_t)(tileN + c * 8 + srow) * DIM + (size_t)t * BK + scol;
    __builtin_amdgcn_global_load_lds(
        (const __attribute__((address_space(1))) void*)(B + g),
        (__attribute__((address_space(3))) void*)(dst + c * 1024), 16, 0, 0);
  };
  // 32x32x32 A/B frag: lane holds row/col (lane&31), K-bytes (lane>>5)*16 within ks*32
  auto rdA32 = [&](const signed char* aL, int m, int ks) -> int4v {
    const int r = wr * 128 + m * 32 + row31;
    return *(const int4v*)(aL + r * BK + ((ks * 32 + khalf * 16) ^ swk));
  };
  auto rdB32 = [&](const signed char* bL, int n, int ks) -> int4v {
    const int r = wc * 64 + n * 32 + row31;
    return *(const int4v*)(bL + r * BK + ((ks * 32 + khalf * 16) ^ swk));
  };

  int16v acc[4][2] = {};   // [m-tile][n-tile], 16 regs each
  int4v af0[2][4];         // A m0-1, [mi][ks]
  int4v af1[2][4];         // A m2-3
  int4v bf[2][4];          // B [n][ks]

#define MFMA_PAIR(AF, MBASE, NH)                                               \
  __builtin_amdgcn_s_setprio(1);                                               \
  _Pragma("unroll") for (int ks = 0; ks < 4; ++ks)                             \
  _Pragma("unroll") for (int mi = 0; mi < 2; ++mi)                             \
      acc[(MBASE) + mi][NH] = __builtin_amdgcn_mfma_i32_32x32x32_i8(           \
          AF[mi][ks], bf[NH][ks], acc[(MBASE) + mi][NH], 0, 0, 0);             \
  __builtin_amdgcn_s_setprio(0);

  // ---- prologue: stage tile0 + tile1; wait tile0 landed; preload af0,bf0 of tile0
#pragma unroll
  for (int i = 0; i < 4; ++i) { stageA(i, 0); stageB(i, 0); }
#pragma unroll
  for (int i = 0; i < 4; ++i) { stageA(i, 1); stageB(i, 1); }
  asm volatile("s_waitcnt vmcnt(8)" ::: "memory");
  __builtin_amdgcn_s_barrier();
  {
    const signed char* a0 = smem;
    const signed char* b0 = smem + 32768;
#pragma unroll
    for (int mi = 0; mi < 2; ++mi)
#pragma unroll
      for (int ks = 0; ks < 4; ++ks) af0[mi][ks] = rdA32(a0, mi, ks);
#pragma unroll
    for (int ks = 0; ks < 4; ++ks) bf[0][ks] = rdB32(b0, 0, ks);
  }

  for (int kt = 0; kt < NKT; ++kt) {
    const signed char* aC = smem + (kt & 1) * 65536;
    const signed char* bC = aC + 32768;
    const signed char* aN = smem + ((kt + 1) & 1) * 65536;
    const signed char* bN = aN + 32768;
    const bool s1 = (kt + 1 < NKT);
    const bool s2 = (kt + 2 < NKT);

    // ---- ph1: issue bf1 (4); wait af0+bf0 (leave bf1 in flight); MFMA m01 x n0
#pragma unroll
    for (int ks = 0; ks < 4; ++ks) bf[1][ks] = rdB32(bC, 1, ks);
    asm volatile("s_waitcnt lgkmcnt(4)" ::: "memory");
    __builtin_amdgcn_sched_barrier(0);
    MFMA_PAIR(af0, 0, 0)

    // ---- ph2: issue af1 (8); wait bf1 (leave af1 in flight); MFMA m01 x n1
#pragma unroll
    for (int mi = 0; mi < 2; ++mi)
#pragma unroll
      for (int ks = 0; ks < 4; ++ks) af1[mi][ks] = rdA32(aC, 2 + mi, ks);
    asm volatile("s_waitcnt lgkmcnt(8)" ::: "memory");
    __builtin_amdgcn_sched_barrier(0);
    MFMA_PAIR(af0, 0, 1)

    // ---- ph3: drain own reads; mid barrier (cur buffer dead block-wide);
    //          stage kt+2 -> cur; MFMA m23 x n0
    asm volatile("s_waitcnt lgkmcnt(0)" ::: "memory");
    __builtin_amdgcn_sched_barrier(0);
    __builtin_amdgcn_s_barrier();
    if (s2) {
#pragma unroll
      for (int i = 0; i < 4; ++i) { stageA(i, kt + 2); stageB(i, kt + 2); }
    }
    __builtin_amdgcn_sched_barrier(0);
    MFMA_PAIR(af1, 2, 0)

    // ---- ph4: counted vmcnt (kt+1 landed, kt+2 in flight); bnd barrier;
    //          issue next-tile af0,bf0 from nxt (overlap MFMA); MFMA m23 x n1
    if (s2) {
      asm volatile("s_waitcnt vmcnt(8)" ::: "memory");
    } else {
      asm volatile("s_waitcnt vmcnt(0)" ::: "memory");
    }
    __builtin_amdgcn_s_barrier();
    if (s1) {
#pragma unroll
      for (int mi = 0; mi < 2; ++mi)
#pragma unroll
        for (int ks = 0; ks < 4; ++ks) af0[mi][ks] = rdA32(aN, mi, ks);
#pragma unroll
      for (int ks = 0; ks < 4; ++ks) bf[0][ks] = rdB32(bN, 0, ks);
    }
    __builtin_amdgcn_sched_barrier(0);
    MFMA_PAIR(af1, 2, 1)
  }

  // ---- epilogue: 32x32 C/D layout: col=lane&31, row=(reg&3)+8*(reg>>2)+4*(lane>>5)
  const float sa = s_act[0];
#pragma unroll
  for (int n = 0; n < 2; ++n) {
    const int col = tileN + wc * 64 + n * 32 + row31;
    const float sc = sa * w_scale[col];
    const float bs = bias[col];
#pragma unroll
    for (int m = 0; m < 4; ++m) {
      const int rbase = tileM + wr * 128 + m * 32 + 4 * khalf;
#pragma unroll
      for (int reg = 0; reg < 16; ++reg) {
        const int row = rbase + (reg & 3) + 8 * (reg >> 2);
        C[(size_t)row * DIM + col] = (float)acc[m][n][reg] * sc + bs;
      }
    }
  }
#undef MFMA_PAIR
}

// ---------------- launch ----------------
extern "C" void kernel_launch(void* const* d_in, const int* in_sizes, int n_in,
                              void* d_out, int out_size, void* d_ws, size_t ws_size,
                              hipStream_t stream) {
  const float* x    = (const float*)d_in[0];
  const float* w    = (const float*)d_in[1];
  const float* bias = (const float*)d_in[2];
  const float* a_s  = (const float*)d_in[3];
  const int*   a_zp = (const int*)d_in[4];
  const float* w_s  = (const float*)d_in[5];
  const int*   w_zp = (const int*)d_in[6];
  float* out = (float*)d_out;

  signed char* a8 = (signed char*)d_ws;
  signed char* b8 = a8 + (size_t)DIM * DIM;

  const int n4 = DIM * DIM / 4;
  quant_act_kernel<<<2048, 256, 0, stream>>>(x, a_s, a_zp, (int*)a8, n4);
  quant_wgt_kernel<<<2048, 256, 0, stream>>>(w, w_s, w_zp, (int*)b8, n4);

  (void)hipFuncSetAttribute((const void*)gemm_i8_32x32,
                            hipFuncAttributeMaxDynamicSharedMemorySize, 131072);
  dim3 grid(DIM / BN, DIM / BM);  // 16 x 16
  gemm_i8_32x32<<<grid, 512, 131072, stream>>>(a8, b8, a_s, w_s, bias, out);
}

// Round 7
// 100.859 us; speedup vs baseline: 1.1427x; 1.1427x over previous
//
#include <hip/hip_runtime.h>
#include <stdint.h>

typedef int   int4v   __attribute__((ext_vector_type(4)));
typedef float float4v __attribute__((ext_vector_type(4)));

static constexpr int DIM = 4096;          // N = IN = OUT
static constexpr int BT  = 128;           // block tile (M and N)
static constexpr int BK  = 128;           // K-step bytes (2 MFMA k-steps of 64)
static constexpr int NKT = DIM / BK;      // 32

// ---------------- quantization kernels ----------------
__global__ __launch_bounds__(256) void quant_act_kernel(
    const float* __restrict__ x, const float* __restrict__ s_ptr,
    const int* __restrict__ zp_ptr, int* __restrict__ out, int n4) {
  const float s  = s_ptr[0];
  const int   zp = zp_ptr[0];
  int idx    = blockIdx.x * blockDim.x + threadIdx.x;
  int stride = gridDim.x * blockDim.x;
  for (int i = idx; i < n4; i += stride) {
    float4v v = reinterpret_cast<const float4v*>(x)[i];
    int packed = 0;
#pragma unroll
    for (int j = 0; j < 4; ++j) {
      int q = (int)rintf(v[j] / s) + zp;
      q = min(max(q, 0), 255);
      q -= zp;
      packed |= (q & 255) << (8 * j);
    }
    out[i] = packed;
  }
}

__global__ __launch_bounds__(256) void quant_wgt_kernel(
    const float* __restrict__ w, const float* __restrict__ ws,
    const int* __restrict__ wzp, int* __restrict__ out, int n4) {
  int idx    = blockIdx.x * blockDim.x + threadIdx.x;
  int stride = gridDim.x * blockDim.x;
  for (int i = idx; i < n4; i += stride) {
    const int row = i >> 10;
    const float s = ws[row];
    const int  zp = wzp[row];
    float4v v = reinterpret_cast<const float4v*>(w)[i];
    int packed = 0;
#pragma unroll
    for (int j = 0; j < 4; ++j) {
      int q = (int)rintf(v[j] / s) + zp;
      q = min(max(q, 0), 255);
      q -= zp;
      packed |= (q & 255) << (8 * j);
    }
    out[i] = packed;
  }
}

// ---- int8 GEMM: 128^2 tile, 8 waves (wave tile 64x32), 64 KiB dbuf LDS ->
//      2 blocks/CU co-resident. Cross-block phase slip provides the LDS<->MFMA
//      overlap that block-wide barriers forbid within one block (m114).
// Per K-tile: stage kt+1 (4 gload_lds/wave) -> read 12 frags -> 16 MFMA ->
// vmcnt(0) + barrier. WAR: reads are consumed by MFMA before the barrier, so
// next iter's staging into this buffer is safe. RAW: vmcnt(0)+barrier.

__global__ __launch_bounds__(512, 4) void gemm_i8_2blk(
    const signed char* __restrict__ A, const signed char* __restrict__ B,
    const float* __restrict__ s_act, const float* __restrict__ w_scale,
    const float* __restrict__ bias, float* __restrict__ C) {
  extern __shared__ signed char smem[];  // 2 x (A 16K + B 16K) = 64 KiB

  const int tid  = threadIdx.x;
  const int w    = tid >> 6;            // wave 0..7
  const int lane = tid & 63;
  const int wr = w >> 2, wc = w & 3;    // 2 x 4 wave grid; wave tile 64x32
  const int l15 = lane & 15, lhi = lane >> 4;
  const int swk = (l15 & 7) << 4;       // read-side XOR swizzle key ((row&7)<<4)

  const int srow = lane >> 3;                           // staging row within 8-row chunk
  const int scol = ((lane & 7) ^ (lane >> 3)) << 4;     // pre-swizzled global col

  const int tileM = blockIdx.y * BT;
  const int tileN = blockIdx.x * BT;

  // chunk c covers tile rows 8c..8c+7 (1 KiB); wave w owns chunks {2w, 2w+1}
  auto stageA = [&](int i, int t) {
    signed char* dst = smem + (t & 1) * 32768;
    const int c = 2 * w + i;
    const size_t g = (size_t)(tileM + c * 8 + srow) * DIM + (size_t)t * BK + scol;
    __builtin_amdgcn_global_load_lds(
        (const __attribute__((address_space(1))) void*)(A + g),
        (__attribute__((address_space(3))) void*)(dst + c * 1024), 16, 0, 0);
  };
  auto stageB = [&](int i, int t) {
    signed char* dst = smem + (t & 1) * 32768 + 16384;
    const int c = 2 * w + i;
    const size_t g = (size_t)(tileN + c * 8 + srow) * DIM + (size_t)t * BK + scol;
    __builtin_amdgcn_global_load_lds(
        (const __attribute__((address_space(1))) void*)(B + g),
        (__attribute__((address_space(3))) void*)(dst + c * 1024), 16, 0, 0);
  };
  auto rdA = [&](const signed char* aL, int m, int kk) -> int4v {
    const int r = wr * 64 + m * 16 + l15;
    return *(const int4v*)(aL + r * BK + ((kk * 64 + lhi * 16) ^ swk));
  };
  auto rdB = [&](const signed char* bL, int n, int kk) -> int4v {
    const int r = wc * 32 + n * 16 + l15;
    return *(const int4v*)(bL + r * BK + ((kk * 64 + lhi * 16) ^ swk));
  };

  int4v acc[4][2] = {};   // [m][n]
  int4v af[4][2];         // [m][kk]
  int4v bf[2][2];         // [n][kk]

  // ---- prologue: stage tile 0 -> buf0
  stageA(0, 0); stageA(1, 0); stageB(0, 0); stageB(1, 0);
  asm volatile("s_waitcnt vmcnt(0)" ::: "memory");
  __builtin_amdgcn_s_barrier();

  for (int kt = 0; kt < NKT; ++kt) {
    const signed char* aC = smem + (kt & 1) * 32768;
    const signed char* bC = aC + 16384;

    // stage kt+1 into the other buffer (in flight during this tile's compute)
    if (kt + 1 < NKT) {
      stageA(0, kt + 1); stageA(1, kt + 1);
      stageB(0, kt + 1); stageB(1, kt + 1);
    }

    // read this tile's fragments (compiler inserts fine-grained lgkmcnt)
#pragma unroll
    for (int m = 0; m < 4; ++m) { af[m][0] = rdA(aC, m, 0); af[m][1] = rdA(aC, m, 1); }
#pragma unroll
    for (int n = 0; n < 2; ++n) { bf[n][0] = rdB(bC, n, 0); bf[n][1] = rdB(bC, n, 1); }

    __builtin_amdgcn_s_setprio(1);
#pragma unroll
    for (int kk = 0; kk < 2; ++kk)
#pragma unroll
      for (int m = 0; m < 4; ++m)
#pragma unroll
        for (int n = 0; n < 2; ++n)
          acc[m][n] = __builtin_amdgcn_mfma_i32_16x16x64_i8(
              af[m][kk], bf[n][kk], acc[m][n], 0, 0, 0);
    __builtin_amdgcn_s_setprio(0);

    asm volatile("s_waitcnt vmcnt(0)" ::: "memory");  // kt+1 landed
    __builtin_amdgcn_s_barrier();                     // all reads consumed; buffers swap
  }

  // ---- epilogue: C/D layout col=lane&15, row=(lane>>4)*4+j
  const float sa = s_act[0];
#pragma unroll
  for (int n = 0; n < 2; ++n) {
    const int col = tileN + wc * 32 + n * 16 + l15;
    const float sc = sa * w_scale[col];
    const float bs = bias[col];
#pragma unroll
    for (int m = 0; m < 4; ++m) {
      const int rbase = tileM + wr * 64 + m * 16 + lhi * 4;
#pragma unroll
      for (int j = 0; j < 4; ++j)
        C[(size_t)(rbase + j) * DIM + col] = (float)acc[m][n][j] * sc + bs;
    }
  }
}

// ---------------- launch ----------------
extern "C" void kernel_launch(void* const* d_in, const int* in_sizes, int n_in,
                              void* d_out, int out_size, void* d_ws, size_t ws_size,
                              hipStream_t stream) {
  const float* x    = (const float*)d_in[0];
  const float* w    = (const float*)d_in[1];
  const float* bias = (const float*)d_in[2];
  const float* a_s  = (const float*)d_in[3];
  const int*   a_zp = (const int*)d_in[4];
  const float* w_s  = (const float*)d_in[5];
  const int*   w_zp = (const int*)d_in[6];
  float* out = (float*)d_out;

  signed char* a8 = (signed char*)d_ws;
  signed char* b8 = a8 + (size_t)DIM * DIM;

  const int n4 = DIM * DIM / 4;
  quant_act_kernel<<<2048, 256, 0, stream>>>(x, a_s, a_zp, (int*)a8, n4);
  quant_wgt_kernel<<<2048, 256, 0, stream>>>(w, w_s, w_zp, (int*)b8, n4);

  (void)hipFuncSetAttribute((const void*)gemm_i8_2blk,
                            hipFuncAttributeMaxDynamicSharedMemorySize, 65536);
  dim3 grid(DIM / BT, DIM / BT);  // 32 x 32 = 1024 blocks -> 2 resident/CU
  gemm_i8_2blk<<<grid, 512, 65536, stream>>>(a8, b8, a_s, w_s, bias, out);
}

// Round 8
// 99.211 us; speedup vs baseline: 1.1617x; 1.0166x over previous
//
#include <hip/hip_runtime.h>
#include <stdint.h>

typedef int   int4v   __attribute__((ext_vector_type(4)));
typedef float float4v __attribute__((ext_vector_type(4)));

static constexpr int DIM = 4096;          // N = IN = OUT
static constexpr int BT  = 128;           // block tile (M and N)
static constexpr int BK  = 128;           // K-step bytes (2 MFMA k-steps of 64)
static constexpr int NKT = DIM / BK;      // 32

// ---------------- quantization kernels ----------------
__global__ __launch_bounds__(256) void quant_act_kernel(
    const float* __restrict__ x, const float* __restrict__ s_ptr,
    const int* __restrict__ zp_ptr, int* __restrict__ out, int n4) {
  const float s  = s_ptr[0];
  const int   zp = zp_ptr[0];
  int idx    = blockIdx.x * blockDim.x + threadIdx.x;
  int stride = gridDim.x * blockDim.x;
  for (int i = idx; i < n4; i += stride) {
    float4v v = reinterpret_cast<const float4v*>(x)[i];
    int packed = 0;
#pragma unroll
    for (int j = 0; j < 4; ++j) {
      int q = (int)rintf(v[j] / s) + zp;
      q = min(max(q, 0), 255);
      q -= zp;
      packed |= (q & 255) << (8 * j);
    }
    out[i] = packed;
  }
}

__global__ __launch_bounds__(256) void quant_wgt_kernel(
    const float* __restrict__ w, const float* __restrict__ ws,
    const int* __restrict__ wzp, int* __restrict__ out, int n4) {
  int idx    = blockIdx.x * blockDim.x + threadIdx.x;
  int stride = gridDim.x * blockDim.x;
  for (int i = idx; i < n4; i += stride) {
    const int row = i >> 10;
    const float s = ws[row];
    const int  zp = wzp[row];
    float4v v = reinterpret_cast<const float4v*>(w)[i];
    int packed = 0;
#pragma unroll
    for (int j = 0; j < 4; ++j) {
      int q = (int)rintf(v[j] / s) + zp;
      q = min(max(q, 0), 255);
      q -= zp;
      packed |= (q & 255) << (8 * j);
    }
    out[i] = packed;
  }
}

// ---- int8 GEMM: 128^2 tile, 4 waves (wave tile 64x64), 64 KiB dbuf LDS ->
//      2 blocks/CU co-resident (cross-block slip = LDS<->MFMA overlap, m114).
// 64x64 wave tile halves LDS read traffic per FLOP vs 64x32 (R7's limiter):
// per K-tile per block: 64 KB reads + 32 KB writes (~750 cy) vs MFMA 653 cy.
// MFMA:ds_read = 32:16 = 2:1. VGPR ~150 -> __launch_bounds__(256,2).

__global__ __launch_bounds__(256, 2) void gemm_i8_w64(
    const signed char* __restrict__ A, const signed char* __restrict__ B,
    const float* __restrict__ s_act, const float* __restrict__ w_scale,
    const float* __restrict__ bias, float* __restrict__ C) {
  extern __shared__ signed char smem[];  // 2 x (A 16K + B 16K) = 64 KiB

  const int tid  = threadIdx.x;
  const int w    = tid >> 6;            // wave 0..3
  const int lane = tid & 63;
  const int wr = w >> 1, wc = w & 1;    // 2 x 2 wave grid; wave tile 64x64
  const int l15 = lane & 15, lhi = lane >> 4;
  const int swk = (l15 & 7) << 4;       // read-side XOR swizzle key ((row&7)<<4)

  const int srow = lane >> 3;                           // staging row within 8-row chunk
  const int scol = ((lane & 7) ^ (lane >> 3)) << 4;     // pre-swizzled global col

  const int tileM = blockIdx.y * BT;
  const int tileN = blockIdx.x * BT;

  // chunk c covers tile rows 8c..8c+7 (1 KiB); wave w owns chunks 4w..4w+3 of A and B
  auto stageA = [&](int i, int t) {
    signed char* dst = smem + (t & 1) * 32768;
    const int c = 4 * w + i;
    const size_t g = (size_t)(tileM + c * 8 + srow) * DIM + (size_t)t * BK + scol;
    __builtin_amdgcn_global_load_lds(
        (const __attribute__((address_space(1))) void*)(A + g),
        (__attribute__((address_space(3))) void*)(dst + c * 1024), 16, 0, 0);
  };
  auto stageB = [&](int i, int t) {
    signed char* dst = smem + (t & 1) * 32768 + 16384;
    const int c = 4 * w + i;
    const size_t g = (size_t)(tileN + c * 8 + srow) * DIM + (size_t)t * BK + scol;
    __builtin_amdgcn_global_load_lds(
        (const __attribute__((address_space(1))) void*)(B + g),
        (__attribute__((address_space(3))) void*)(dst + c * 1024), 16, 0, 0);
  };
  auto rdA = [&](const signed char* aL, int m, int kk) -> int4v {
    const int r = wr * 64 + m * 16 + l15;
    return *(const int4v*)(aL + r * BK + ((kk * 64 + lhi * 16) ^ swk));
  };
  auto rdB = [&](const signed char* bL, int n, int kk) -> int4v {
    const int r = wc * 64 + n * 16 + l15;
    return *(const int4v*)(bL + r * BK + ((kk * 64 + lhi * 16) ^ swk));
  };

  int4v acc[4][4] = {};   // [m][n]
  int4v af[4][2];         // [m][kk]
  int4v bf[4][2];         // [n][kk]

  // ---- prologue: stage tile 0 -> buf0
#pragma unroll
  for (int i = 0; i < 4; ++i) { stageA(i, 0); stageB(i, 0); }
  asm volatile("s_waitcnt vmcnt(0)" ::: "memory");
  __builtin_amdgcn_s_barrier();

  for (int kt = 0; kt < NKT; ++kt) {
    const signed char* aC = smem + (kt & 1) * 32768;
    const signed char* bC = aC + 16384;

    // stage kt+1 into the other buffer (in flight during this tile's compute)
    if (kt + 1 < NKT) {
#pragma unroll
      for (int i = 0; i < 4; ++i) { stageA(i, kt + 1); stageB(i, kt + 1); }
    }

    // read this tile's fragments (compiler inserts fine-grained lgkmcnt)
#pragma unroll
    for (int m = 0; m < 4; ++m) { af[m][0] = rdA(aC, m, 0); af[m][1] = rdA(aC, m, 1); }
#pragma unroll
    for (int n = 0; n < 4; ++n) { bf[n][0] = rdB(bC, n, 0); bf[n][1] = rdB(bC, n, 1); }

    __builtin_amdgcn_s_setprio(1);
#pragma unroll
    for (int kk = 0; kk < 2; ++kk)
#pragma unroll
      for (int m = 0; m < 4; ++m)
#pragma unroll
        for (int n = 0; n < 4; ++n)
          acc[m][n] = __builtin_amdgcn_mfma_i32_16x16x64_i8(
              af[m][kk], bf[n][kk], acc[m][n], 0, 0, 0);
    __builtin_amdgcn_s_setprio(0);

    asm volatile("s_waitcnt vmcnt(0)" ::: "memory");  // kt+1 landed
    __builtin_amdgcn_s_barrier();                     // all reads consumed; buffers swap
  }

  // ---- epilogue: C/D layout col=lane&15, row=(lane>>4)*4+j
  const float sa = s_act[0];
#pragma unroll
  for (int n = 0; n < 4; ++n) {
    const int col = tileN + wc * 64 + n * 16 + l15;
    const float sc = sa * w_scale[col];
    const float bs = bias[col];
#pragma unroll
    for (int m = 0; m < 4; ++m) {
      const int rbase = tileM + wr * 64 + m * 16 + lhi * 4;
#pragma unroll
      for (int j = 0; j < 4; ++j)
        C[(size_t)(rbase + j) * DIM + col] = (float)acc[m][n][j] * sc + bs;
    }
  }
}

// ---------------- launch ----------------
extern "C" void kernel_launch(void* const* d_in, const int* in_sizes, int n_in,
                              void* d_out, int out_size, void* d_ws, size_t ws_size,
                              hipStream_t stream) {
  const float* x    = (const float*)d_in[0];
  const float* w    = (const float*)d_in[1];
  const float* bias = (const float*)d_in[2];
  const float* a_s  = (const float*)d_in[3];
  const int*   a_zp = (const int*)d_in[4];
  const float* w_s  = (const float*)d_in[5];
  const int*   w_zp = (const int*)d_in[6];
  float* out = (float*)d_out;

  signed char* a8 = (signed char*)d_ws;
  signed char* b8 = a8 + (size_t)DIM * DIM;

  const int n4 = DIM * DIM / 4;
  quant_act_kernel<<<2048, 256, 0, stream>>>(x, a_s, a_zp, (int*)a8, n4);
  quant_wgt_kernel<<<2048, 256, 0, stream>>>(w, w_s, w_zp, (int*)b8, n4);

  (void)hipFuncSetAttribute((const void*)gemm_i8_w64,
                            hipFuncAttributeMaxDynamicSharedMemorySize, 65536);
  dim3 grid(DIM / BT, DIM / BT);  // 32 x 32 = 1024 blocks -> 2 resident/CU
  gemm_i8_w64<<<grid, 256, 65536, stream>>>(a8, b8, a_s, w_s, bias, out);
}